// Round 5
// baseline (715.801 us; speedup 1.0000x reference)
//
#include <hip/hip_runtime.h>
#include <cstdint>

// ---------------------------------------------------------------------------
// ConvModule: LN -> GEMM(512->1024)+SiLU -> conv K=5 (1024->1024) -> GLU ->
//             BN -> GEMM(512->512).  B=16, T=1024, C=512. fp32 I/O, bf16 MFMA.
// Round 5: barrier-free per-wave A staging + full-iteration B/A register
// prefetch (latency ~390cyc covered by ~390cyc of MFMA per iteration).
// ---------------------------------------------------------------------------

#define NB    16
#define TT    1024
#define CC    512
#define C2    1024
#define TPAD  1028        // T + 4 pad rows (2 each side) per batch

typedef unsigned short u16;
typedef short bf16x8 __attribute__((ext_vector_type(8)));
typedef float f32x4  __attribute__((ext_vector_type(4)));

__device__ __forceinline__ float bf2f(u16 u) {
  union { unsigned int i; float f; } v; v.i = ((unsigned int)u) << 16; return v.f;
}
__device__ __forceinline__ u16 f2bf(float f) {
  union { float f; unsigned int i; } v; v.f = f;
  unsigned int x = v.i;
  return (u16)((x + 0x7fffu + ((x >> 16) & 1u)) >> 16);  // RNE
}

// ---------------------------------------------------------------------------
__global__ __launch_bounds__(256) void cvt_f2b(
    const float* __restrict__ in, u16* __restrict__ out) {
  const int i = (blockIdx.x * 256 + threadIdx.x) * 4;
  float4 v = *(const float4*)(in + i);
  u16 o[4] = { f2bf(v.x), f2bf(v.y), f2bf(v.z), f2bf(v.w) };
  *(uint2*)(out + i) = *(const uint2*)o;
}

// ---------------------------------------------------------------------------
__global__ void zero_pads(u16* __restrict__ h1p) {
  const int idx = blockIdx.x * 256 + threadIdx.x;
  const int bb  = idx >> 9;
  const int rem = idx & 511;
  const int ri  = rem >> 7;
  const int c8  = (rem & 127) * 8;
  const int row = bb * TPAD + (ri < 2 ? ri : 1024 + ri);   // 0,1,1026,1027
  uint4 z = make_uint4(0u, 0u, 0u, 0u);
  *(uint4*)(h1p + (size_t)row * C2 + c8) = z;
}

// ---------------------------------------------------------------------------
// w2 fp32 (K, I, O) -> w2t bf16 (K, O, I)
__global__ void transpose_w2(const float* __restrict__ w2, u16* __restrict__ w2t) {
  __shared__ u16 t[64][65];
  const int k  = blockIdx.z;
  const int i0 = blockIdx.x * 64, o0 = blockIdx.y * 64;
  const int tx = threadIdx.x, ty = threadIdx.y;
  for (int r = ty; r < 64; r += 4)
    t[r][tx] = f2bf(w2[((size_t)(k * C2) + i0 + r) * C2 + o0 + tx]);
  __syncthreads();
  for (int r = ty; r < 64; r += 4)
    w2t[((size_t)(k * C2) + o0 + r) * C2 + i0 + tx] = t[tx][r];
}

// ---------------------------------------------------------------------------
__global__ __launch_bounds__(256) void layernorm_k(
    const float* __restrict__ x, const float* __restrict__ lng,
    const float* __restrict__ lnb, u16* __restrict__ out) {
  const int tok  = blockIdx.x * 4 + (threadIdx.x >> 6);
  const int lane = threadIdx.x & 63;
  const float* xp = x + (size_t)tok * CC + lane * 8;
  float f[8];
  *(float4*)(f)     = *(const float4*)(xp);
  *(float4*)(f + 4) = *(const float4*)(xp + 4);
  float s = 0.f, s2 = 0.f;
#pragma unroll
  for (int j = 0; j < 8; j++) { s += f[j]; s2 += f[j] * f[j]; }
#pragma unroll
  for (int m = 32; m >= 1; m >>= 1) { s += __shfl_xor(s, m, 64); s2 += __shfl_xor(s2, m, 64); }
  const float mu  = s  * (1.f / 512.f);
  const float var = s2 * (1.f / 512.f) - mu * mu;
  const float rs  = rsqrtf(var + 1e-5f);
  u16 ov[8];
#pragma unroll
  for (int j = 0; j < 8; j++) {
    const int c = lane * 8 + j;
    ov[j] = f2bf((f[j] - mu) * rs * lng[c] + lnb[c]);
  }
  *(uint4*)(out + (size_t)tok * CC + lane * 8) = *(const uint4*)ov;
}

// ---------------------------------------------------------------------------
// GEMM out[m,n] = sum_k A[m,k]*Bt[n,k] + bias[n].  128x128 tile, BK=32.
// Barrier-free: each wave stages its own 64-row A slice (double-buffered,
// stride-40), B frags direct global with depth-2 rotation (Bf[2][4]),
// A global->reg prefetch depth-2 (rAq[2][4]).  EPI as before.
template <int EPI>
__global__ __launch_bounds__(256, 2) void gemm_bt(
    const u16* __restrict__ A, const u16* __restrict__ Bt,
    const float* __restrict__ bias, void* __restrict__ outv,
    const int Kd, const int ldA) {
  __shared__ __align__(16) u16 smem[20480];     // 4 waves x 2 bufs x 64x40
  const int tid  = threadIdx.x;
  const int m0   = blockIdx.x * 128;
  const int n0   = blockIdx.y * 128;
  const int wave = tid >> 6, lane = tid & 63;
  const int wm = (wave & 1) * 64, wn = (wave >> 1) * 64;
  const int quad = lane >> 4, l16 = lane & 15;
  const int srow = lane >> 2;          // 0..15 (+p*16)
  const int scol = (lane & 3) * 8;     // 0/8/16/24
  u16* wbuf = smem + wave * 5120;
  const int J = Kd >> 5;

  const u16* Ap = A + (size_t)(m0 + wm) * ldA + scol;
  const u16* Bp = Bt + (size_t)(n0 + wn + l16) * Kd + quad * 8;

  f32x4 acc[4][4] = {};
  uint4 rAq[2][4];
#pragma unroll
  for (int p = 0; p < 4; p++)
    rAq[0][p] = *(const uint4*)(Ap + (size_t)(p * 16 + srow) * ldA);
#pragma unroll
  for (int p = 0; p < 4; p++)
    *(uint4*)(wbuf + (p * 16 + srow) * 40 + scol) = rAq[0][p];
#pragma unroll
  for (int p = 0; p < 4; p++)
    rAq[1][p] = *(const uint4*)(Ap + (size_t)(p * 16 + srow) * ldA + 32);
#pragma unroll
  for (int p = 0; p < 4; p++)
    rAq[0][p] = *(const uint4*)(Ap + (size_t)(p * 16 + srow) * ldA + 64);
  bf16x8 Bf[2][4];
#pragma unroll
  for (int i = 0; i < 4; i++) Bf[0][i] = *(const bf16x8*)(Bp + (size_t)i * 16 * Kd);
#pragma unroll
  for (int i = 0; i < 4; i++) Bf[1][i] = *(const bf16x8*)(Bp + (size_t)i * 16 * Kd + 32);

#define GEMM_ITER(SLOT, J_)                                                   \
  {                                                                           \
    const int j = (J_);                                                       \
    const int k0 = j * 32;                                                    \
    const u16* cur = wbuf + (SLOT) * 2560;                                    \
    if (j + 1 < J) {                                                          \
      u16* nxt = wbuf + (1 - (SLOT)) * 2560;                                  \
      _Pragma("unroll")                                                       \
      for (int p = 0; p < 4; p++)                                             \
        *(uint4*)(nxt + (p * 16 + srow) * 40 + scol) = rAq[1 - (SLOT)][p];    \
      if (j + 3 < J) {                                                        \
        _Pragma("unroll")                                                     \
        for (int p = 0; p < 4; p++)                                           \
          rAq[1 - (SLOT)][p] =                                                \
              *(const uint4*)(Ap + (size_t)(p * 16 + srow) * ldA + k0 + 96);  \
      }                                                                       \
    }                                                                         \
    bf16x8 af[4];                                                             \
    _Pragma("unroll")                                                         \
    for (int i = 0; i < 4; i++)                                               \
      af[i] = *(const bf16x8*)(cur + (i * 16 + l16) * 40 + quad * 8);         \
    _Pragma("unroll")                                                         \
    for (int mi = 0; mi < 4; mi++)                                            \
      _Pragma("unroll")                                                       \
      for (int ni = 0; ni < 4; ni++)                                          \
        acc[mi][ni] = __builtin_amdgcn_mfma_f32_16x16x32_bf16(                \
            af[mi], Bf[SLOT][ni], acc[mi][ni], 0, 0, 0);                      \
    if (j + 2 < J) {                                                          \
      _Pragma("unroll")                                                       \
      for (int i = 0; i < 4; i++)                                             \
        Bf[SLOT][i] = *(const bf16x8*)(Bp + (size_t)i * 16 * Kd + k0 + 64);   \
    }                                                                         \
  }

#pragma unroll 1
  for (int jj = 0; jj < J; jj += 2) {
    GEMM_ITER(0, jj)
    GEMM_ITER(1, jj + 1)
  }
#undef GEMM_ITER

  float bv[4];
#pragma unroll
  for (int ni = 0; ni < 4; ni++) bv[ni] = bias[n0 + wn + ni * 16 + l16];

  if (EPI == 0) {
    u16* epi = wbuf;                     // 64 x 72 u16 (4608 <= 5120)
#pragma unroll
    for (int mi = 0; mi < 4; mi++)
#pragma unroll
      for (int ni = 0; ni < 4; ni++)
#pragma unroll
        for (int r = 0; r < 4; r++) {
          float v = acc[mi][ni][r] + bv[ni];
          v = v / (1.f + __expf(-v));    // SiLU
          epi[(mi * 16 + quad * 4 + r) * 72 + ni * 16 + l16] = f2bf(v);
        }
    u16* h1p = (u16*)outv;
#pragma unroll
    for (int p = 0; p < 8; p++) {
      const int rrow = p * 8 + (lane >> 3);
      const int colb = (lane & 7) * 8;
      uint4 v = *(const uint4*)(epi + rrow * 72 + colb);
      const int rr = m0 + wm + rrow;
      const int bb = rr >> 10, tt = rr & 1023;
      *(uint4*)(h1p + (size_t)(bb * TPAD + tt + 2) * C2 + n0 + wn + colb) = v;
    }
  } else {
    float* fepi = (float*)wbuf;          // 2 x (16 x 68) f32 (8704B <= 10240B)
    float* outf = (float*)outv;
#pragma unroll
    for (int mi = 0; mi < 4; mi++) {
      float* fp = fepi + (mi & 1) * 1088;
#pragma unroll
      for (int ni = 0; ni < 4; ni++)
#pragma unroll
        for (int r = 0; r < 4; r++)
          fp[(quad * 4 + r) * 68 + ni * 16 + l16] = acc[mi][ni][r] + bv[ni];
#pragma unroll
      for (int p = 0; p < 4; p++) {
        const int rrow = p * 4 + (lane >> 4);
        const int col  = (lane & 15) * 4;
        float4 v = *(const float4*)(fp + rrow * 68 + col);
        *(float4*)(outf + (size_t)(m0 + wm + mi * 16 + rrow) * CC + n0 + wn + col) = v;
      }
    }
  }
}

// ---------------------------------------------------------------------------
// 5-tap conv, barrier-free: each wave stages its own 68-row (64+4 halo) A
// slice double-buffered; all 20 B frags held in regs (Bf[5][4]) and reloaded
// tap-by-tap right after use -> full-iteration prefetch distance (~390 cyc).
__global__ __launch_bounds__(256, 2) void conv5_mfma(
    const u16* __restrict__ h1p, const u16* __restrict__ w2t,
    const float* __restrict__ b2, u16* __restrict__ out) {
  __shared__ __align__(16) u16 smem[21760];     // 4 waves x 2 bufs x 68x40
  const int tid = threadIdx.x;
  const int mt  = blockIdx.x;
  const int n0  = blockIdx.y * 128;
  const int bb  = mt >> 3;
  const int t0  = (mt & 7) * 128;
  const size_t arow0 = (size_t)bb * TPAD + t0;
  const int wave = tid >> 6, lane = tid & 63;
  const int wm = (wave & 1) * 64, wn = (wave >> 1) * 64;
  const int quad = lane >> 4, l16 = lane & 15;
  const int srow = lane >> 2;          // 0..15 (+p*16); p=4 uses lanes<16
  const int scol = (lane & 3) * 8;
  u16* wbuf = smem + wave * 5440;

  const u16* Ab = h1p + (arow0 + wm) * C2 + scol;
  const u16* Bb = w2t + (size_t)(n0 + wn + l16) * C2 + quad * 8;

  f32x4 acc[4][4] = {};
  uint4 rA[5];
#pragma unroll
  for (int p = 0; p < 5; p++)
    if (p < 4 || lane < 16)
      rA[p] = *(const uint4*)(Ab + (size_t)(p * 16 + srow) * C2);
#pragma unroll
  for (int p = 0; p < 5; p++)
    if (p < 4 || lane < 16)
      *(uint4*)(wbuf + (p * 16 + srow) * 40 + scol) = rA[p];
#pragma unroll
  for (int p = 0; p < 5; p++)
    if (p < 4 || lane < 16)
      rA[p] = *(const uint4*)(Ab + (size_t)(p * 16 + srow) * C2 + 32);
  bf16x8 Bf[5][4];
#pragma unroll
  for (int k = 0; k < 5; k++)
#pragma unroll
    for (int i = 0; i < 4; i++)
      Bf[k][i] = *(const bf16x8*)(Bb + (size_t)k * C2 * C2 + (size_t)i * 16 * C2);

#pragma unroll 1
  for (int j = 0; j < 32; j++) {
    const int i0 = j * 32;
    const u16* cur = wbuf + (j & 1) * 2720;
    if (j + 1 < 32) {
      u16* nxt = wbuf + ((j + 1) & 1) * 2720;
#pragma unroll
      for (int p = 0; p < 5; p++)
        if (p < 4 || lane < 16)
          *(uint4*)(nxt + (p * 16 + srow) * 40 + scol) = rA[p];
      if (j + 2 < 32) {
#pragma unroll
        for (int p = 0; p < 5; p++)
          if (p < 4 || lane < 16)
            rA[p] = *(const uint4*)(Ab + (size_t)(p * 16 + srow) * C2 + i0 + 64);
      }
    }
#pragma unroll
    for (int k = 0; k < 5; k++) {
      bf16x8 af[4];
#pragma unroll
      for (int i = 0; i < 4; i++)
        af[i] = *(const bf16x8*)(cur + (i * 16 + l16 + k) * 40 + quad * 8);
#pragma unroll
      for (int mi = 0; mi < 4; mi++)
#pragma unroll
        for (int ni = 0; ni < 4; ni++)
          acc[mi][ni] = __builtin_amdgcn_mfma_f32_16x16x32_bf16(
              af[mi], Bf[k][ni], acc[mi][ni], 0, 0, 0);
      if (j + 1 < 32) {
#pragma unroll
        for (int i = 0; i < 4; i++)
          Bf[k][i] = *(const bf16x8*)(Bb + (size_t)k * C2 * C2 +
                                      (size_t)i * 16 * C2 + i0 + 32);
      }
    }
  }

  float bv[4];
#pragma unroll
  for (int ni = 0; ni < 4; ni++) bv[ni] = b2[n0 + wn + ni * 16 + l16];

  u16* epi = wbuf;                       // 64 x 72 u16 (4608 <= 5440)
#pragma unroll
  for (int mi = 0; mi < 4; mi++)
#pragma unroll
    for (int ni = 0; ni < 4; ni++)
#pragma unroll
      for (int r = 0; r < 4; r++)
        epi[(mi * 16 + quad * 4 + r) * 72 + ni * 16 + l16] = f2bf(acc[mi][ni][r] + bv[ni]);

  const size_t orow0 = (size_t)bb * TT + t0;
#pragma unroll
  for (int p = 0; p < 8; p++) {
    const int rrow = p * 8 + (lane >> 3);
    const int colb = (lane & 7) * 8;
    uint4 v = *(const uint4*)(epi + rrow * 72 + colb);
    *(uint4*)(out + (orow0 + wm + rrow) * C2 + n0 + wn + colb) = v;
  }
}

// ---------------------------------------------------------------------------
__global__ __launch_bounds__(256) void glu_bn_k(
    const u16* __restrict__ hc, const float* __restrict__ bg,
    const float* __restrict__ bb_, const float* __restrict__ bm,
    const float* __restrict__ bv, u16* __restrict__ out) {
  const int idx = blockIdx.x * 256 + threadIdx.x;
  const int r  = idx >> 6;
  const int c8 = (idx & 63) * 8;
  const u16* pa = hc + (size_t)r * C2 + c8;
  uint4 ra = *(const uint4*)pa;
  uint4 rg = *(const uint4*)(pa + CC);
  u16 av[8], gv[8], ov[8];
  *(uint4*)av = ra; *(uint4*)gv = rg;
#pragma unroll
  for (int j = 0; j < 8; j++) {
    const int c = c8 + j;
    const float a = bf2f(av[j]);
    const float g = bf2f(gv[j]);
    const float h = a / (1.f + __expf(-g));
    const float sc = bg[c] * rsqrtf(bv[c] + 1e-5f);
    ov[j] = f2bf((h - bm[c]) * sc + bb_[c]);
  }
  *(uint4*)(out + (size_t)r * CC + c8) = *(const uint4*)ov;
}

// ---------------------------------------------------------------------------
extern "C" void kernel_launch(void* const* d_in, const int* in_sizes, int n_in,
                              void* d_out, int out_size, void* d_ws, size_t ws_size,
                              hipStream_t stream) {
  const float* x   = (const float*)d_in[0];
  const float* lng = (const float*)d_in[1];
  const float* lnb = (const float*)d_in[2];
  const float* w1  = (const float*)d_in[3];
  const float* b1  = (const float*)d_in[4];
  const float* w2  = (const float*)d_in[5];
  const float* b2  = (const float*)d_in[6];
  const float* bng = (const float*)d_in[7];
  const float* bnb = (const float*)d_in[8];
  const float* bnm = (const float*)d_in[9];
  const float* bnv = (const float*)d_in[10];
  const float* w3  = (const float*)d_in[11];
  const float* b3  = (const float*)d_in[12];

  u16* ws  = (u16*)d_ws;
  u16* hln = ws;                               // 16384*512
  u16* h2  = hln;                              // alias (hln dead after GEMM1)
  u16* h1p = ws + 8388608;                     // 16*1028*1024
  u16* w2t = h1p + 16842752;                   // 5*1024*1024
  u16* hcv = w2t + 5242880;                    // 16384*1024
  u16* w1b = hcv + 16777216;                   // 1024*512
  u16* w3b = w1b + 524288;                     // 512*512

  zero_pads   <<<32, 256, 0, stream>>>(h1p);
  cvt_f2b     <<<512, 256, 0, stream>>>(w1, w1b);
  cvt_f2b     <<<256, 256, 0, stream>>>(w3, w3b);
  transpose_w2<<<dim3(16, 16, 5), dim3(64, 4), 0, stream>>>(w2, w2t);
  layernorm_k <<<4096, 256, 0, stream>>>(x, lng, lnb, hln);
  gemm_bt<0>  <<<dim3(128, 8), 256, 0, stream>>>(hln, w1b, b1, h1p, 512, 512);
  conv5_mfma  <<<dim3(128, 8), 256, 0, stream>>>(h1p, w2t, b2, hcv);
  glu_bn_k    <<<4096, 256, 0, stream>>>(hcv, bng, bnb, bnm, bnv, h2);
  gemm_bt<1>  <<<dim3(128, 4), 256, 0, stream>>>(h2, w3b, b3, d_out, 512, 512);
}